// Round 1
// 88.058 us; speedup vs baseline: 1.1101x; 1.1101x over previous
//
#include <hip/hip_runtime.h>

#define DD 128
#define NN 512

// ---------------------------------------------------------------------------
// Kernel 1: fused prep + per-row pipeline. 256 blocks x 512 threads, 8 rows/blk.
//  Entry:   issue adj row loads (1 wave = 1 row, 2x int4/lane) -> overlap P.
//  phase P: 4-way k-split of cb/v1 matvecs (q = t>>7, wave-uniform):
//             q0: E0@W1a   q1: nc@W1b   q2: te[t[b]]@W1c   q3: (E1-E0)@W1a
//           128 L2 loads/thread (was 256 at 1 wave/SIMD -> latency-bound).
//  phase A: finish popcount -> p[r] per row (wave64 reduce).
//  phase B: preHf partials: thread = (dh = t>>6 in 0..7 -> 16 d's, c0 = 2 cols)
//           h recomputed in-register; W2 read once per block, float2/lane.
//  phase C: combine 8 partials (stride-1 b32 LDS reads, conflict-free),
//           relu(+b2), project on Wc -> li/lj; bc folded into li.
// ---------------------------------------------------------------------------
__global__ __launch_bounds__(512) void rows_kernel(
    const int* __restrict__ adj,
    const int* __restrict__ tt,
    const float* __restrict__ time_embed,
    const float* __restrict__ no_cond,
    const float* __restrict__ edge_embed,
    const float* __restrict__ W1,
    const float* __restrict__ b1,
    const float* __restrict__ W2,
    const float* __restrict__ b2,
    const float* __restrict__ Wc,
    const float* __restrict__ bc,
    float* __restrict__ ws_li,   // [2048*2]  (bc pre-added)
    float* __restrict__ ws_lj)   // [2048*2]
{
    __shared__ float sP[8 * 8 * DD];   // [r][dh][c] partial preHf, 32 KB
    __shared__ float s_part[512];      // phase-P partials [q][d]
    __shared__ float s_cb[DD];
    __shared__ float s_v1[DD];
    __shared__ float s_p[8];

    const int t = threadIdx.x;
    const int lane = t & 63;
    const int wv = t >> 6;            // wave id 0..7
    const int row0 = blockIdx.x * 8;
    const int b = blockIdx.x >> 6;

    // --- phase A issue: wave wv owns adj row row0+wv; loads fly during P ---
    const int4* abase = (const int4*)(adj + (size_t)(row0 + wv) * NN);
    int4 a0 = abase[lane];
    int4 a1 = abase[lane + 64];

    // --- phase P: 4-way k-split, 128 iters/thread, W1 from L2 ---
    {
        const int d = t & 127;
        const int q = t >> 7;         // wave-uniform
        float c = 0.f;
        if (q == 0) {
            const float* wp = W1 + d;
#pragma unroll 8
            for (int k = 0; k < 128; ++k)
                c = fmaf(edge_embed[k], wp[k * DD], c);
        } else if (q == 1) {
            const float* wp = W1 + 128 * DD + d;
#pragma unroll 8
            for (int k = 0; k < 128; ++k)
                c = fmaf(no_cond[k], wp[k * DD], c);
        } else if (q == 2) {
            const float* teb = time_embed + (size_t)tt[b] * DD;
            const float* wp = W1 + 256 * DD + d;
#pragma unroll 8
            for (int k = 0; k < 128; ++k)
                c = fmaf(teb[k], wp[k * DD], c);
        } else {
            const float* wp = W1 + d;
#pragma unroll 8
            for (int k = 0; k < 128; ++k)
                c = fmaf(edge_embed[DD + k] - edge_embed[k], wp[k * DD], c);
        }
        s_part[t] = c;
    }

    // --- phase A finish: popcount -> p[r] ---
    {
        int s = a0.x + a0.y + a0.z + a0.w + a1.x + a1.y + a1.z + a1.w;
#pragma unroll
        for (int off = 32; off; off >>= 1) s += __shfl_xor(s, off, 64);
        if (lane == 0) s_p[wv] = (float)s * (1.0f / (float)NN);
    }
    __syncthreads();

    if (t < DD) {
        s_cb[t] = s_part[t] + s_part[t + 128] + s_part[t + 256] + b1[t];
        s_v1[t] = s_part[t + 384];
    }
    __syncthreads();

    float p[8];
#pragma unroll
    for (int r = 0; r < 8; ++r) p[r] = s_p[r];

    // --- phase B: partial matvec. thread = (cols c0..c0+1, d chunk dh of 16) ---
    const int cg = t & 63;
    const int dh = t >> 6;            // 0..7
    const int c0 = cg * 2;
    float acc[8][2];
#pragma unroll
    for (int r = 0; r < 8; ++r) { acc[r][0] = 0.f; acc[r][1] = 0.f; }

    const float2* W2v = (const float2*)W2;
#pragma unroll
    for (int i = 0; i < 16; ++i) {
        const int d = dh * 16 + i;
        float2 w = W2v[(d * DD + c0) >> 1];
        float cbd = s_cb[d];
        float v1d = s_v1[d];
#pragma unroll
        for (int r = 0; r < 8; ++r) {
            float h = fmaxf(fmaf(p[r], v1d, cbd), 0.f);
            acc[r][0] = fmaf(h, w.x, acc[r][0]);
            acc[r][1] = fmaf(h, w.y, acc[r][1]);
        }
    }
#pragma unroll
    for (int r = 0; r < 8; ++r)
        *(float2*)&sP[(r * 8 + dh) * DD + c0] = make_float2(acc[r][0], acc[r][1]);
    __syncthreads();

    // --- phase C: combine. wave wv -> row wv; lane -> cols lane, lane+64 ---
    float s0 = 0.f, s1 = 0.f;
#pragma unroll
    for (int k = 0; k < 8; ++k) {
        const float* rowp = &sP[(wv * 8 + k) * DD];
        s0 += rowp[lane];
        s1 += rowp[lane + 64];
    }
    float f0 = fmaxf(s0 + b2[lane], 0.f);
    float f1 = fmaxf(s1 + b2[lane + 64], 0.f);

    const float2* Wc2 = (const float2*)Wc;
    float2 wa0 = Wc2[lane];
    float2 wa1 = Wc2[lane + 64];
    float2 wb0 = Wc2[DD + lane];
    float2 wb1 = Wc2[DD + lane + 64];

    float li0 = f0 * wa0.x + f1 * wa1.x;
    float li1 = f0 * wa0.y + f1 * wa1.y;
    float lj0 = f0 * wb0.x + f1 * wb1.x;
    float lj1 = f0 * wb0.y + f1 * wb1.y;

#pragma unroll
    for (int off = 32; off; off >>= 1) {
        li0 += __shfl_xor(li0, off, 64);
        li1 += __shfl_xor(li1, off, 64);
        lj0 += __shfl_xor(lj0, off, 64);
        lj1 += __shfl_xor(lj1, off, 64);
    }
    if (lane == 0) {
        int row = row0 + wv;
        *(float2*)&ws_li[row * 2] = make_float2(li0 + bc[0], li1 + bc[1]);
        *(float2*)&ws_lj[row * 2] = make_float2(lj0, lj1);
    }
}

// ---------------------------------------------------------------------------
// Kernel 2: logits[b,i,j,c] = li[b,i,c] + lj[b,j,c]   (bc pre-folded into li)
// Grid: 1024 blocks x 256 threads. Block covers 2 i-rows; thread stores 8 f32.
// ---------------------------------------------------------------------------
__global__ __launch_bounds__(256) void write_kernel(
    const float* __restrict__ ws_li,
    const float* __restrict__ ws_lj,
    float* __restrict__ out)
{
    const int blk = blockIdx.x;           // 0..1023
    const int t = threadIdx.x;
    const int b = blk >> 8;
    const int i = (blk & 255) * 2 + (t >> 7);
    const int j0 = (t & 127) * 4;

    float2 li = *(const float2*)&ws_li[(b * NN + i) * 2];
    float a0 = li.x;
    float a1 = li.y;

    float4 L0 = *(const float4*)&ws_lj[(b * NN + j0) * 2];       // rows j0, j0+1
    float4 L1 = *(const float4*)&ws_lj[(b * NN + j0 + 2) * 2];   // rows j0+2, j0+3

    float4 o0 = make_float4(a0 + L0.x, a1 + L0.y, a0 + L0.z, a1 + L0.w);
    float4 o1 = make_float4(a0 + L1.x, a1 + L1.y, a0 + L1.z, a1 + L1.w);

    size_t base = (((size_t)(b * NN + i)) * NN + j0) * 2;   // f32 element index
    *(float4*)&out[base]     = o0;
    *(float4*)&out[base + 4] = o1;
}

extern "C" void kernel_launch(void* const* d_in, const int* in_sizes, int n_in,
                              void* d_out, int out_size, void* d_ws, size_t ws_size,
                              hipStream_t stream) {
    const int*   adj = (const int*)d_in[0];
    const int*   tt  = (const int*)d_in[1];
    const float* te  = (const float*)d_in[2];
    const float* nc  = (const float*)d_in[3];
    const float* ee  = (const float*)d_in[4];
    const float* W1  = (const float*)d_in[5];
    const float* b1  = (const float*)d_in[6];
    const float* W2  = (const float*)d_in[7];
    const float* b2  = (const float*)d_in[8];
    const float* Wc  = (const float*)d_in[9];
    const float* bc  = (const float*)d_in[10];
    float* out = (float*)d_out;

    float* ws    = (float*)d_ws;
    float* ws_li = ws;            // 4096 floats
    float* ws_lj = ws + 4096;     // 4096 floats

    rows_kernel<<<256, 512, 0, stream>>>(adj, tt, te, nc, ee, W1, b1, W2, b2,
                                         Wc, bc, ws_li, ws_lj);
    write_kernel<<<1024, 256, 0, stream>>>(ws_li, ws_lj, out);
}